// Round 14
// baseline (170.376 us; speedup 1.0000x reference)
//
#include <hip/hip_runtime.h>

typedef _Float16 f16;
typedef __fp16 fp16x2 __attribute__((ext_vector_type(2)));
typedef _Float16 half4 __attribute__((ext_vector_type(4)));
typedef _Float16 half8 __attribute__((ext_vector_type(8)));
typedef float f32x4 __attribute__((ext_vector_type(4)));
typedef float float4v __attribute__((ext_vector_type(4)));
typedef float float2v __attribute__((ext_vector_type(2)));

#define LOG2E 1.44269504088896340736f

union H8 { fp16x2 h2[4]; half8 h8; };
union HV { half8 h8; half4 h4[2]; };

__device__ __forceinline__ float rowmax16(const f32x4 sf[4]) {
    float a = fmaxf(fmaxf(sf[0][0], sf[0][1]), fmaxf(sf[0][2], sf[0][3]));
    float b = fmaxf(fmaxf(sf[1][0], sf[1][1]), fmaxf(sf[1][2], sf[1][3]));
    float c = fmaxf(fmaxf(sf[2][0], sf[2][1]), fmaxf(sf[2][2], sf[2][3]));
    float d = fmaxf(fmaxf(sf[3][0], sf[3][1]), fmaxf(sf[3][2], sf[3][3]));
    return fmaxf(fmaxf(a, b), fmaxf(c, d));
}

// running-max update with defer threshold; rescales o and the MFMA-held l.
__device__ __forceinline__ void max_defer(
    const f32x4 sf[4], float& mL, f32x4 o[4], f32x4& la)
{
    float vm = rowmax16(sf);
    vm = fmaxf(vm, __shfl_xor(vm, 16, 64));
    vm = fmaxf(vm, __shfl_xor(vm, 32, 64));
    float vmL = vm * LOG2E;
    if (__any(vmL > mL + 8.0f)) {
        float mn = fmaxf(mL, vmL);
        float al = __builtin_amdgcn_exp2f(mL - mn);
        la *= al;
        #pragma unroll
        for (int db = 0; db < 4; ++db) o[db] *= al;
        mL = mn;
    }
}

// P = exp2(S*log2e - mL), packed to fp16 B-fragments (pure VALU, no lgkm).
__device__ __forceinline__ void exp_pack(
    const f32x4 sf[4], float mL, H8& pb0, H8& pb1)
{
    float pe[16];
    #pragma unroll
    for (int kb = 0; kb < 4; ++kb)
        #pragma unroll
        for (int ro = 0; ro < 4; ++ro)
            pe[kb * 4 + ro] = __builtin_amdgcn_exp2f(fmaf(sf[kb][ro], LOG2E, -mL));
    pb0.h2[0] = __builtin_amdgcn_cvt_pkrtz(pe[0],  pe[1]);
    pb0.h2[1] = __builtin_amdgcn_cvt_pkrtz(pe[2],  pe[3]);
    pb0.h2[2] = __builtin_amdgcn_cvt_pkrtz(pe[4],  pe[5]);
    pb0.h2[3] = __builtin_amdgcn_cvt_pkrtz(pe[6],  pe[7]);
    pb1.h2[0] = __builtin_amdgcn_cvt_pkrtz(pe[8],  pe[9]);
    pb1.h2[1] = __builtin_amdgcn_cvt_pkrtz(pe[10], pe[11]);
    pb1.h2[2] = __builtin_amdgcn_cvt_pkrtz(pe[12], pe[13]);
    pb1.h2[3] = __builtin_amdgcn_cvt_pkrtz(pe[14], pe[15]);
}

// ---------------------------------------------------------------------------
// QKV projection. Q,K written (b,h,s,dd); V written TRANSPOSED (b,h,dd,s)
// so flash can stage V^T tiles row-major (no LDS transpose-reads).
// ---------------------------------------------------------------------------
__global__ __launch_bounds__(256) void qkv_proj(
    const float* __restrict__ Aq, const float* __restrict__ Ak, const float* __restrict__ Av,
    const float* __restrict__ Wq, const float* __restrict__ Wk, const float* __restrict__ Wv,
    const float* __restrict__ bq, const float* __restrict__ bk, const float* __restrict__ bv,
    f16* __restrict__ Qh, f16* __restrict__ Kh, f16* __restrict__ Vt)
{
    const int z = blockIdx.z;
    const float* __restrict__ A    = (z == 0) ? Aq : (z == 1) ? Ak : Av;
    const float* __restrict__ W    = (z == 0) ? Wq : (z == 1) ? Wk : Wv;
    const float* __restrict__ bias = (z == 0) ? bq : (z == 1) ? bk : bv;
    f16* __restrict__ dst          = (z == 0) ? Qh : (z == 1) ? Kh : Vt;

    __shared__ __align__(16) f16 As[128 * 40];
    __shared__ __align__(16) f16 Ws[128 * 40];

    const int t  = threadIdx.x;
    const int m0 = blockIdx.y * 128;
    const int n0 = blockIdx.x * 128;
    const int w = t >> 6, lane = t & 63, lr = lane & 15, lg = lane >> 4;
    const int wr = w >> 1, wc = w & 1;

    f32x4 acc[4][4] = {};

    for (int k0 = 0; k0 < 512; k0 += 32) {
        #pragma unroll
        for (int it = 0; it < 2; ++it) {
            int c = t + it * 256;
            int row  = c >> 2;
            int col8 = (c & 3) * 8;

            const float* ga = A + (size_t)(m0 + row) * 512 + k0 + col8;
            float4v a0 = *(const float4v*)ga;
            float4v a1 = *(const float4v*)(ga + 4);
            half8 ha;
            ha[0] = (f16)a0[0]; ha[1] = (f16)a0[1]; ha[2] = (f16)a0[2]; ha[3] = (f16)a0[3];
            ha[4] = (f16)a1[0]; ha[5] = (f16)a1[1]; ha[6] = (f16)a1[2]; ha[7] = (f16)a1[3];
            *(half8*)&As[row * 40 + col8] = ha;

            const float* gw = W + (size_t)(n0 + row) * 512 + k0 + col8;
            float4v w0 = *(const float4v*)gw;
            float4v w1 = *(const float4v*)(gw + 4);
            half8 hw;
            hw[0] = (f16)w0[0]; hw[1] = (f16)w0[1]; hw[2] = (f16)w0[2]; hw[3] = (f16)w0[3];
            hw[4] = (f16)w1[0]; hw[5] = (f16)w1[1]; hw[6] = (f16)w1[2]; hw[7] = (f16)w1[3];
            *(half8*)&Ws[row * 40 + col8] = hw;
        }
        __syncthreads();

        half8 af[4], bf[4];
        #pragma unroll
        for (int i = 0; i < 4; ++i) {
            af[i] = *(const half8*)&As[(wr * 64 + i * 16 + lr) * 40 + lg * 8];
            bf[i] = *(const half8*)&Ws[(wc * 64 + i * 16 + lr) * 40 + lg * 8];
        }
        #pragma unroll
        for (int mi = 0; mi < 4; ++mi)
            #pragma unroll
            for (int ni = 0; ni < 4; ++ni)
                acc[mi][ni] = __builtin_amdgcn_mfma_f32_16x16x32_f16(af[mi], bf[ni], acc[mi][ni], 0, 0, 0);
        __syncthreads();
    }

    if (z == 2) {
        // V: transposed store Vt[((b*8+h)*64 + dd)*4096 + s], half4 over r
        #pragma unroll
        for (int mi = 0; mi < 4; ++mi) {
            #pragma unroll
            for (int ni = 0; ni < 4; ++ni) {
                int col = n0 + wc * 64 + ni * 16 + lr;
                float bv_ = bias[col];
                int h  = col >> 6;
                int dd = col & 63;
                int row0 = m0 + wr * 64 + mi * 16 + lg * 4;   // 4-aligned
                int b  = row0 >> 12;
                int s0 = row0 & 4095;
                half4 hv;
                hv[0] = (f16)(acc[mi][ni][0] + bv_);
                hv[1] = (f16)(acc[mi][ni][1] + bv_);
                hv[2] = (f16)(acc[mi][ni][2] + bv_);
                hv[3] = (f16)(acc[mi][ni][3] + bv_);
                *(half4*)&dst[(((size_t)(b * 8 + h)) * 64 + dd) * 4096 + s0] = hv;
            }
        }
    } else {
        #pragma unroll
        for (int mi = 0; mi < 4; ++mi) {
            #pragma unroll
            for (int ni = 0; ni < 4; ++ni) {
                int col = n0 + wc * 64 + ni * 16 + lr;
                float bv_ = bias[col];
                int h  = col >> 6;
                int dd = col & 63;
                #pragma unroll
                for (int r = 0; r < 4; ++r) {
                    int row = m0 + wr * 64 + mi * 16 + lg * 4 + r;
                    int b = row >> 12;
                    int s = row & 4095;
                    dst[(((size_t)(b * 8 + h)) * 4096 + s) * 64 + dd] = (f16)(acc[mi][ni][r] + bv_);
                }
            }
        }
    }
}

// ---------------------------------------------------------------------------
// Flash attention v12 = round-13 kernel with the V path re-plumbed:
// V comes pre-transposed from HBM (Vt[bh][dd][s]); staged row-major into
// Vs[dd][slot] (stride 72) with the PV key-permutation applied at staging
// (slot(k) = 32k5 + 16k3 + 8k2 + 4k4 + 2k1 + k0), so PV A-fragments are
// plain ds_read_b128 (kf pattern, conflict-free). tr_b16 reads + fences
// GONE -> bank conflicts (1.47e7, ~55% of DS pipe) eliminated.
// ---------------------------------------------------------------------------
__global__ __launch_bounds__(256, 2) void flash_attn(
    const f16* __restrict__ Qh, const f16* __restrict__ Kh, const f16* __restrict__ Vt,
    f16* __restrict__ Xp, float2v* __restrict__ mlp)
{
    const int bh  = blockIdx.y;           // 0..15  (b*8 + h)
    const int z   = blockIdx.z;           // KV half
    const int t = threadIdx.x, w = t >> 6, lane = t & 63, lr = lane & 15, lg = lane >> 4;
    const int q0 = blockIdx.x * 128 + w * 32;

    __shared__ __align__(16) f16 Ks[2][64 * 72];   // [key][d], stride 72
    __shared__ __align__(16) f16 Vs[2][64 * 72];   // [dd][slot], stride 72

    const size_t hb = (size_t)bh * (4096 * 64);

    // Q fragments (B-operand of swapped QK^T) for both 16-row groups
    half8 aq00 = *(const half8*)&Qh[hb + (size_t)(q0 + lr) * 64 + lg * 8];
    half8 aq01 = *(const half8*)&Qh[hb + (size_t)(q0 + lr) * 64 + 32 + lg * 8];
    half8 aq10 = *(const half8*)&Qh[hb + (size_t)(q0 + 16 + lr) * 64 + lg * 8];
    half8 aq11 = *(const half8*)&Qh[hb + (size_t)(q0 + 16 + lr) * 64 + 32 + lg * 8];

    // loop-invariant MFMA constants
    half8 ones;
    #pragma unroll
    for (int j = 0; j < 8; ++j) ones[j] = (f16)1.0f;
    const f32x4 zf = {0.0f, 0.0f, 0.0f, 0.0f};

    // staging: 256 threads x 2 rows x 8 f16 per buffer
    const int srow = t >> 3;            // K: key idx / V: dd idx (0..31, +32)
    const int u    = t & 7;
    const int scol = u * 8;
    const int kdstA = srow * 72 + scol;
    const int kdstB = kdstA + 32 * 72;
    // V slot base for the 8 keys u*8..u*8+7: 32*u2 + 16*u0 + 4*u1
    const int vposb = ((u >> 2) & 1) * 32 + (u & 1) * 16 + ((u >> 1) & 1) * 4;
    const int vdstA = srow * 72 + vposb;
    const int vdstB = vdstA + 32 * 72;

    f32x4 o0[4] = {}, o1[4] = {};
    f32x4 la0 = {}, la1 = {};           // l accumulators in MFMA D-layout
    float mL0 = -INFINITY, mL1 = -INFINITY;

    const f16* kbase = Kh + hb + (size_t)(z * 2048 + srow) * 64 + scol;
    const f16* vbase = Vt + hb + (size_t)srow * 4096 + z * 2048 + scol;

    half8 kregA = *(const half8*)kbase;
    half8 kregB = *(const half8*)(kbase + 2048);
    half8 vregA = *(const half8*)vbase;
    half8 vregB = *(const half8*)(vbase + (size_t)32 * 4096);

    for (int kt = 0; kt < 2048; kt += 64) {
        const int bi = (kt >> 6) & 1;
        f16* ks = &Ks[bi][0];
        f16* vs = &Vs[bi][0];

        *(half8*)&ks[kdstA] = kregA;
        *(half8*)&ks[kdstB] = kregB;
        {   // permuted V slot writes: two half4 chunks per 8-key load
            HV a_; a_.h8 = vregA;
            *(half4*)&vs[vdstA]     = a_.h4[0];
            *(half4*)&vs[vdstA + 8] = a_.h4[1];
            HV b_; b_.h8 = vregB;
            *(half4*)&vs[vdstB]     = b_.h4[0];
            *(half4*)&vs[vdstB + 8] = b_.h4[1];
        }
        __syncthreads();

        // prefetch next tile into regs (hides HBM under compute)
        int koff = ((kt + 64) & 2047);
        kregA = *(const half8*)(kbase + (size_t)koff * 64);
        kregB = *(const half8*)(kbase + 2048 + (size_t)koff * 64);
        vregA = *(const half8*)(vbase + koff);
        vregB = *(const half8*)(vbase + (size_t)32 * 4096 + koff);

        // ---- S^T = K Q^T for both q-groups; kf loaded once, used twice ----
        f32x4 sf0[4], sf1[4];
        {
            half8 kf[4];
            #pragma unroll
            for (int kb = 0; kb < 4; ++kb)
                kf[kb] = *(const half8*)&ks[(kb * 16 + lr) * 72 + lg * 8];
            __builtin_amdgcn_s_setprio(1);
            #pragma unroll
            for (int kb = 0; kb < 4; ++kb)
                sf0[kb] = __builtin_amdgcn_mfma_f32_16x16x32_f16(kf[kb], aq00, zf, 0, 0, 0);
            #pragma unroll
            for (int kb = 0; kb < 4; ++kb)
                sf1[kb] = __builtin_amdgcn_mfma_f32_16x16x32_f16(kf[kb], aq10, zf, 0, 0, 0);
            __builtin_amdgcn_s_setprio(0);
            #pragma unroll
            for (int kb = 0; kb < 4; ++kb)
                kf[kb] = *(const half8*)&ks[(kb * 16 + lr) * 72 + 32 + lg * 8];
            __builtin_amdgcn_s_setprio(1);
            #pragma unroll
            for (int kb = 0; kb < 4; ++kb)
                sf0[kb] = __builtin_amdgcn_mfma_f32_16x16x32_f16(kf[kb], aq01, sf0[kb], 0, 0, 0);
            #pragma unroll
            for (int kb = 0; kb < 4; ++kb)
                sf1[kb] = __builtin_amdgcn_mfma_f32_16x16x32_f16(kf[kb], aq11, sf1[kb], 0, 0, 0);
            __builtin_amdgcn_s_setprio(0);
        }

        // ---- max-reduce + defer ----
        max_defer(sf0, mL0, o0, la0);
        max_defer(sf1, mL1, o1, la1);

        // ---- read V^T A-fragments (plain b128, conflict-free); exp/pack
        //      VALU hides the LDS latency ----
        half8 va[4], vb_[4];
        #pragma unroll
        for (int db = 0; db < 4; ++db) {
            va[db]  = *(const half8*)&vs[(db * 16 + lr) * 72 + lg * 8];
            vb_[db] = *(const half8*)&vs[(db * 16 + lr) * 72 + 32 + lg * 8];
        }

        H8 p00, p01, p10, p11;
        exp_pack(sf0, mL0, p00, p01);
        exp_pack(sf1, mL1, p10, p11);

        // ---- O^T += V^T P^T ; l += ones x P (MFMA row-sum) ----
        __builtin_amdgcn_s_setprio(1);
        o0[0] = __builtin_amdgcn_mfma_f32_16x16x32_f16(va[0], p00.h8, o0[0], 0, 0, 0);
        o0[1] = __builtin_amdgcn_mfma_f32_16x16x32_f16(va[1], p00.h8, o0[1], 0, 0, 0);
        o0[2] = __builtin_amdgcn_mfma_f32_16x16x32_f16(va[2], p00.h8, o0[2], 0, 0, 0);
        o0[3] = __builtin_amdgcn_mfma_f32_16x16x32_f16(va[3], p00.h8, o0[3], 0, 0, 0);
        o1[0] = __builtin_amdgcn_mfma_f32_16x16x32_f16(va[0], p10.h8, o1[0], 0, 0, 0);
        o1[1] = __builtin_amdgcn_mfma_f32_16x16x32_f16(va[1], p10.h8, o1[1], 0, 0, 0);
        o1[2] = __builtin_amdgcn_mfma_f32_16x16x32_f16(va[2], p10.h8, o1[2], 0, 0, 0);
        o1[3] = __builtin_amdgcn_mfma_f32_16x16x32_f16(va[3], p10.h8, o1[3], 0, 0, 0);
        la0 = __builtin_amdgcn_mfma_f32_16x16x32_f16(ones, p00.h8, la0, 0, 0, 0);
        la1 = __builtin_amdgcn_mfma_f32_16x16x32_f16(ones, p10.h8, la1, 0, 0, 0);
        o0[0] = __builtin_amdgcn_mfma_f32_16x16x32_f16(vb_[0], p01.h8, o0[0], 0, 0, 0);
        o0[1] = __builtin_amdgcn_mfma_f32_16x16x32_f16(vb_[1], p01.h8, o0[1], 0, 0, 0);
        o0[2] = __builtin_amdgcn_mfma_f32_16x16x32_f16(vb_[2], p01.h8, o0[2], 0, 0, 0);
        o0[3] = __builtin_amdgcn_mfma_f32_16x16x32_f16(vb_[3], p01.h8, o0[3], 0, 0, 0);
        o1[0] = __builtin_amdgcn_mfma_f32_16x16x32_f16(vb_[0], p11.h8, o1[0], 0, 0, 0);
        o1[1] = __builtin_amdgcn_mfma_f32_16x16x32_f16(vb_[1], p11.h8, o1[1], 0, 0, 0);
        o1[2] = __builtin_amdgcn_mfma_f32_16x16x32_f16(vb_[2], p11.h8, o1[2], 0, 0, 0);
        o1[3] = __builtin_amdgcn_mfma_f32_16x16x32_f16(vb_[3], p11.h8, o1[3], 0, 0, 0);
        la0 = __builtin_amdgcn_mfma_f32_16x16x32_f16(ones, p01.h8, la0, 0, 0, 0);
        la1 = __builtin_amdgcn_mfma_f32_16x16x32_f16(ones, p11.h8, la1, 0, 0, 0);
        __builtin_amdgcn_s_setprio(0);
    }

    // ---- epilogue: partial X_z = O/l (no /8 here), write (b, s, h, dd) ----
    const int b = bh >> 3, h = bh & 7;
    f16* X = Xp + (size_t)z * (8192 * 512);
    const float inv0 = 1.0f / la0[0];
    const float inv1 = 1.0f / la1[0];
    const int q0_ = q0 + lr, q1_ = q0 + 16 + lr;
    #pragma unroll
    for (int db = 0; db < 4; ++db) {
        half4 hv0, hv1;
        hv0[0] = (f16)(o0[db][0] * inv0);
        hv0[1] = (f16)(o0[db][1] * inv0);
        hv0[2] = (f16)(o0[db][2] * inv0);
        hv0[3] = (f16)(o0[db][3] * inv0);
        *(half4*)&X[((size_t)(b * 4096 + q0_)) * 512 + h * 64 + db * 16 + lg * 4] = hv0;
        hv1[0] = (f16)(o1[db][0] * inv1);
        hv1[1] = (f16)(o1[db][1] * inv1);
        hv1[2] = (f16)(o1[db][2] * inv1);
        hv1[3] = (f16)(o1[db][3] * inv1);
        *(half4*)&X[((size_t)(b * 4096 + q1_)) * 512 + h * 64 + db * 16 + lg * 4] = hv1;
    }

    // (m, l) per q-row: lanes 0..15 hold la[0] = l(q0+lr); mL wave-uniform.
    if (lane < 16) {
        float2v m0v; m0v[0] = mL0; m0v[1] = la0[0];
        float2v m1v; m1v[0] = mL1; m1v[1] = la1[0];
        mlp[(size_t)z * 65536 + bh * 4096 + q0_] = m0v;
        mlp[(size_t)z * 65536 + bh * 4096 + q1_] = m1v;
    }
}

// ---------------------------------------------------------------------------
// Output projection with fused combine (unchanged from round 13).
// ---------------------------------------------------------------------------
__global__ __launch_bounds__(256) void out_proj(
    const f16* __restrict__ Xp, const float2v* __restrict__ mlp,
    const float* __restrict__ Wo, const float* __restrict__ bo,
    float* __restrict__ out)
{
    __shared__ __align__(16) f16 As[128 * 40];
    __shared__ __align__(16) f16 Ws[128 * 40];

    const int t  = threadIdx.x;
    const int m0 = blockIdx.y * 128;
    const int n0 = blockIdx.x * 128;
    const int w = t >> 6, lane = t & 63, lr = lane & 15, lg = lane >> 4;
    const int wr = w >> 1, wc = w & 1;

    f32x4 acc[4][4] = {};

    for (int k0 = 0; k0 < 512; k0 += 32) {
        #pragma unroll
        for (int it = 0; it < 2; ++it) {
            int c = t + it * 256;
            int row  = c >> 2;
            int col8 = (c & 3) * 8;
            int gcol = k0 + col8;          // h*64+dd ; h constant over 8 elems
            int tok  = m0 + row;

            // combine weights for (token, h)
            int bhq = ((tok >> 12) * 8 + (gcol >> 6)) * 4096 + (tok & 4095);
            float2v ml1 = mlp[bhq];
            float2v ml2 = mlp[65536 + bhq];
            float mm = fmaxf(ml1[0], ml2[0]);
            float a1 = __builtin_amdgcn_exp2f(ml1[0] - mm) * ml1[1];
            float a2 = __builtin_amdgcn_exp2f(ml2[0] - mm) * ml2[1];
            float inv = 1.0f / (8.0f * (a1 + a2));   // /8 = /sqrt(d_k)
            float w1 = a1 * inv, w2 = a2 * inv;

            const size_t xoff = (size_t)tok * 512 + gcol;
            half8 x1 = *(const half8*)&Xp[xoff];
            half8 x2 = *(const half8*)&Xp[(size_t)8192 * 512 + xoff];
            half8 hx;
            #pragma unroll
            for (int j = 0; j < 8; ++j)
                hx[j] = (f16)(w1 * (float)x1[j] + w2 * (float)x2[j]);
            *(half8*)&As[row * 40 + col8] = hx;

            const float* gw = Wo + (size_t)(n0 + row) * 512 + k0 + col8;
            float4v w0 = *(const float4v*)gw;
            float4v w1v = *(const float4v*)(gw + 4);
            half8 hw;
            hw[0] = (f16)w0[0];  hw[1] = (f16)w0[1];  hw[2] = (f16)w0[2];  hw[3] = (f16)w0[3];
            hw[4] = (f16)w1v[0]; hw[5] = (f16)w1v[1]; hw[6] = (f16)w1v[2]; hw[7] = (f16)w1v[3];
            *(half8*)&Ws[row * 40 + col8] = hw;
        }
        __syncthreads();

        half8 af[4], bf[4];
        #pragma unroll
        for (int i = 0; i < 4; ++i) {
            af[i] = *(const half8*)&As[(wr * 64 + i * 16 + lr) * 40 + lg * 8];
            bf[i] = *(const half8*)&Ws[(wc * 64 + i * 16 + lr) * 40 + lg * 8];
        }
        #pragma unroll
        for (int mi = 0; mi < 4; ++mi)
            #pragma unroll
            for (int ni = 0; ni < 4; ++ni)
                acc[mi][ni] = __builtin_amdgcn_mfma_f32_16x16x32_f16(af[mi], bf[ni], acc[mi][ni], 0, 0, 0);
        __syncthreads();
    }

    #pragma unroll
    for (int mi = 0; mi < 4; ++mi) {
        #pragma unroll
        for (int ni = 0; ni < 4; ++ni) {
            int col = n0 + wc * 64 + ni * 16 + lr;
            float bb = bo[col];
            #pragma unroll
            for (int r = 0; r < 4; ++r) {
                int row = m0 + wr * 64 + mi * 16 + lg * 4 + r;
                out[(size_t)row * 512 + col] = acc[mi][ni][r] + bb;
            }
        }
    }
}

// ---------------------------------------------------------------------------
extern "C" void kernel_launch(void* const* d_in, const int* in_sizes, int n_in,
                              void* d_out, int out_size, void* d_ws, size_t ws_size,
                              hipStream_t stream) {
    const float* query = (const float*)d_in[0];
    const float* key   = (const float*)d_in[1];
    const float* value = (const float*)d_in[2];
    const float* Wq    = (const float*)d_in[3];
    const float* bq    = (const float*)d_in[4];
    const float* Wk    = (const float*)d_in[5];
    const float* bk    = (const float*)d_in[6];
    const float* Wv    = (const float*)d_in[7];
    const float* bv    = (const float*)d_in[8];
    const float* Wo    = (const float*)d_in[9];
    const float* bo    = (const float*)d_in[10];
    float* out = (float*)d_out;

    char* ws = (char*)d_ws;
    f16*     Qh  = (f16*)(ws);                      //  0 MB, 8 MB
    f16*     Kh  = (f16*)(ws + 8388608);            //  8 MB, 8 MB
    f16*     Vt  = (f16*)(ws + 16777216);           // 16 MB, 8 MB (transposed)
    f16*     Xp  = (f16*)(ws + 25165824);           // 24 MB, 16 MB (2 halves)
    float2v* mlp = (float2v*)(ws + 41943040);       // 40 MB, 1 MB

    qkv_proj<<<dim3(4, 64, 3), 256, 0, stream>>>(query, key, value,
                                                 Wq, Wk, Wv, bq, bk, bv,
                                                 Qh, Kh, Vt);
    flash_attn<<<dim3(32, 16, 2), 256, 0, stream>>>(Qh, Kh, Vt, Xp, mlp);
    out_proj<<<dim3(4, 64), 256, 0, stream>>>(Xp, mlp, Wo, bo, out);
}

// Round 15
// 167.239 us; speedup vs baseline: 1.0188x; 1.0188x over previous
//
#include <hip/hip_runtime.h>

typedef _Float16 f16;
typedef __fp16 fp16x2 __attribute__((ext_vector_type(2)));
typedef _Float16 half4 __attribute__((ext_vector_type(4)));
typedef _Float16 half8 __attribute__((ext_vector_type(8)));
typedef float f32x4 __attribute__((ext_vector_type(4)));
typedef float float4v __attribute__((ext_vector_type(4)));
typedef float float2v __attribute__((ext_vector_type(2)));

#define LOG2E 1.44269504088896340736f

union H8 { fp16x2 h2[4]; half8 h8; };
union HV { half8 h8; half4 h4[2]; };

__device__ __forceinline__ float rowmax16(const f32x4 sf[4]) {
    float a = fmaxf(fmaxf(sf[0][0], sf[0][1]), fmaxf(sf[0][2], sf[0][3]));
    float b = fmaxf(fmaxf(sf[1][0], sf[1][1]), fmaxf(sf[1][2], sf[1][3]));
    float c = fmaxf(fmaxf(sf[2][0], sf[2][1]), fmaxf(sf[2][2], sf[2][3]));
    float d = fmaxf(fmaxf(sf[3][0], sf[3][1]), fmaxf(sf[3][2], sf[3][3]));
    return fmaxf(fmaxf(a, b), fmaxf(c, d));
}

// running-max update with defer threshold; rescales o and the MFMA-held l.
__device__ __forceinline__ void max_defer(
    const f32x4 sf[4], float& mL, f32x4 o[4], f32x4& la)
{
    float vm = rowmax16(sf);
    vm = fmaxf(vm, __shfl_xor(vm, 16, 64));
    vm = fmaxf(vm, __shfl_xor(vm, 32, 64));
    float vmL = vm * LOG2E;
    if (__any(vmL > mL + 8.0f)) {
        float mn = fmaxf(mL, vmL);
        float al = __builtin_amdgcn_exp2f(mL - mn);
        la *= al;
        #pragma unroll
        for (int db = 0; db < 4; ++db) o[db] *= al;
        mL = mn;
    }
}

// P = exp2(S*log2e - mL), packed to fp16 B-fragments (pure VALU, no lgkm).
__device__ __forceinline__ void exp_pack(
    const f32x4 sf[4], float mL, H8& pb0, H8& pb1)
{
    float pe[16];
    #pragma unroll
    for (int kb = 0; kb < 4; ++kb)
        #pragma unroll
        for (int ro = 0; ro < 4; ++ro)
            pe[kb * 4 + ro] = __builtin_amdgcn_exp2f(fmaf(sf[kb][ro], LOG2E, -mL));
    pb0.h2[0] = __builtin_amdgcn_cvt_pkrtz(pe[0],  pe[1]);
    pb0.h2[1] = __builtin_amdgcn_cvt_pkrtz(pe[2],  pe[3]);
    pb0.h2[2] = __builtin_amdgcn_cvt_pkrtz(pe[4],  pe[5]);
    pb0.h2[3] = __builtin_amdgcn_cvt_pkrtz(pe[6],  pe[7]);
    pb1.h2[0] = __builtin_amdgcn_cvt_pkrtz(pe[8],  pe[9]);
    pb1.h2[1] = __builtin_amdgcn_cvt_pkrtz(pe[10], pe[11]);
    pb1.h2[2] = __builtin_amdgcn_cvt_pkrtz(pe[12], pe[13]);
    pb1.h2[3] = __builtin_amdgcn_cvt_pkrtz(pe[14], pe[15]);
}

// ---------------------------------------------------------------------------
// Weight pre-conversion: Wq,Wk,Wv,Wo (512x512 fp32) -> f16, concatenated.
// ---------------------------------------------------------------------------
__global__ __launch_bounds__(256) void wcvt(
    const float* __restrict__ Wq, const float* __restrict__ Wk,
    const float* __restrict__ Wv, const float* __restrict__ Wo,
    f16* __restrict__ dst)
{
    const int m = blockIdx.y;
    const float* __restrict__ src = (m == 0) ? Wq : (m == 1) ? Wk : (m == 2) ? Wv : Wo;
    const size_t i = ((size_t)blockIdx.x * 256 + threadIdx.x) * 8;
    float4v a0 = *(const float4v*)(src + i);
    float4v a1 = *(const float4v*)(src + i + 4);
    half8 h;
    h[0] = (f16)a0[0]; h[1] = (f16)a0[1]; h[2] = (f16)a0[2]; h[3] = (f16)a0[3];
    h[4] = (f16)a1[0]; h[5] = (f16)a1[1]; h[6] = (f16)a1[2]; h[7] = (f16)a1[3];
    *(half8*)&dst[(size_t)m * 262144 + i] = h;
}

// ---------------------------------------------------------------------------
// QKV projection. W staged from pre-converted f16 (1 load + 1 write, no cvt).
// Q,K written (b,h,s,dd); V written TRANSPOSED (b,h,dd,s).
// ---------------------------------------------------------------------------
__global__ __launch_bounds__(256) void qkv_proj(
    const float* __restrict__ Aq, const float* __restrict__ Ak, const float* __restrict__ Av,
    const f16* __restrict__ Wh,
    const float* __restrict__ bq, const float* __restrict__ bk, const float* __restrict__ bv,
    f16* __restrict__ Qh, f16* __restrict__ Kh, f16* __restrict__ Vt)
{
    const int z = blockIdx.z;
    const float* __restrict__ A    = (z == 0) ? Aq : (z == 1) ? Ak : Av;
    const f16*   __restrict__ W    = Wh + (size_t)z * 262144;
    const float* __restrict__ bias = (z == 0) ? bq : (z == 1) ? bk : bv;
    f16* __restrict__ dst          = (z == 0) ? Qh : (z == 1) ? Kh : Vt;

    __shared__ __align__(16) f16 As[128 * 40];
    __shared__ __align__(16) f16 Ws[128 * 40];

    const int t  = threadIdx.x;
    const int m0 = blockIdx.y * 128;
    const int n0 = blockIdx.x * 128;
    const int w = t >> 6, lane = t & 63, lr = lane & 15, lg = lane >> 4;
    const int wr = w >> 1, wc = w & 1;

    f32x4 acc[4][4] = {};

    for (int k0 = 0; k0 < 512; k0 += 32) {
        #pragma unroll
        for (int it = 0; it < 2; ++it) {
            int c = t + it * 256;
            int row  = c >> 2;
            int col8 = (c & 3) * 8;

            const float* ga = A + (size_t)(m0 + row) * 512 + k0 + col8;
            float4v a0 = *(const float4v*)ga;
            float4v a1 = *(const float4v*)(ga + 4);
            half8 ha;
            ha[0] = (f16)a0[0]; ha[1] = (f16)a0[1]; ha[2] = (f16)a0[2]; ha[3] = (f16)a0[3];
            ha[4] = (f16)a1[0]; ha[5] = (f16)a1[1]; ha[6] = (f16)a1[2]; ha[7] = (f16)a1[3];
            *(half8*)&As[row * 40 + col8] = ha;

            *(half8*)&Ws[row * 40 + col8] =
                *(const half8*)&W[(size_t)(n0 + row) * 512 + k0 + col8];
        }
        __syncthreads();

        half8 af[4], bf[4];
        #pragma unroll
        for (int i = 0; i < 4; ++i) {
            af[i] = *(const half8*)&As[(wr * 64 + i * 16 + lr) * 40 + lg * 8];
            bf[i] = *(const half8*)&Ws[(wc * 64 + i * 16 + lr) * 40 + lg * 8];
        }
        #pragma unroll
        for (int mi = 0; mi < 4; ++mi)
            #pragma unroll
            for (int ni = 0; ni < 4; ++ni)
                acc[mi][ni] = __builtin_amdgcn_mfma_f32_16x16x32_f16(af[mi], bf[ni], acc[mi][ni], 0, 0, 0);
        __syncthreads();
    }

    if (z == 2) {
        // V: transposed store Vt[((b*8+h)*64 + dd)*4096 + s], half4 over r
        #pragma unroll
        for (int mi = 0; mi < 4; ++mi) {
            #pragma unroll
            for (int ni = 0; ni < 4; ++ni) {
                int col = n0 + wc * 64 + ni * 16 + lr;
                float bv_ = bias[col];
                int h  = col >> 6;
                int dd = col & 63;
                int row0 = m0 + wr * 64 + mi * 16 + lg * 4;   // 4-aligned
                int b  = row0 >> 12;
                int s0 = row0 & 4095;
                half4 hv;
                hv[0] = (f16)(acc[mi][ni][0] + bv_);
                hv[1] = (f16)(acc[mi][ni][1] + bv_);
                hv[2] = (f16)(acc[mi][ni][2] + bv_);
                hv[3] = (f16)(acc[mi][ni][3] + bv_);
                *(half4*)&dst[(((size_t)(b * 8 + h)) * 64 + dd) * 4096 + s0] = hv;
            }
        }
    } else {
        #pragma unroll
        for (int mi = 0; mi < 4; ++mi) {
            #pragma unroll
            for (int ni = 0; ni < 4; ++ni) {
                int col = n0 + wc * 64 + ni * 16 + lr;
                float bv_ = bias[col];
                int h  = col >> 6;
                int dd = col & 63;
                #pragma unroll
                for (int r = 0; r < 4; ++r) {
                    int row = m0 + wr * 64 + mi * 16 + lg * 4 + r;
                    int b = row >> 12;
                    int s = row & 4095;
                    dst[(((size_t)(b * 8 + h)) * 4096 + s) * 64 + dd] = (f16)(acc[mi][ni][r] + bv_);
                }
            }
        }
    }
}

// ---------------------------------------------------------------------------
// Flash attention (round-14 kernel verbatim, 108 us): KV-split over z,
// V pre-transposed in HBM, Vs staged row-major with PV key-permutation,
// plain ds_read_b128 PV fragments (no tr_b16).
// ---------------------------------------------------------------------------
__global__ __launch_bounds__(256, 2) void flash_attn(
    const f16* __restrict__ Qh, const f16* __restrict__ Kh, const f16* __restrict__ Vt,
    f16* __restrict__ Xp, float2v* __restrict__ mlp)
{
    const int bh  = blockIdx.y;           // 0..15  (b*8 + h)
    const int z   = blockIdx.z;           // KV half
    const int t = threadIdx.x, w = t >> 6, lane = t & 63, lr = lane & 15, lg = lane >> 4;
    const int q0 = blockIdx.x * 128 + w * 32;

    __shared__ __align__(16) f16 Ks[2][64 * 72];   // [key][d], stride 72
    __shared__ __align__(16) f16 Vs[2][64 * 72];   // [dd][slot], stride 72

    const size_t hb = (size_t)bh * (4096 * 64);

    // Q fragments (B-operand of swapped QK^T) for both 16-row groups
    half8 aq00 = *(const half8*)&Qh[hb + (size_t)(q0 + lr) * 64 + lg * 8];
    half8 aq01 = *(const half8*)&Qh[hb + (size_t)(q0 + lr) * 64 + 32 + lg * 8];
    half8 aq10 = *(const half8*)&Qh[hb + (size_t)(q0 + 16 + lr) * 64 + lg * 8];
    half8 aq11 = *(const half8*)&Qh[hb + (size_t)(q0 + 16 + lr) * 64 + 32 + lg * 8];

    // loop-invariant MFMA constants
    half8 ones;
    #pragma unroll
    for (int j = 0; j < 8; ++j) ones[j] = (f16)1.0f;
    const f32x4 zf = {0.0f, 0.0f, 0.0f, 0.0f};

    // staging: 256 threads x 2 rows x 8 f16 per buffer
    const int srow = t >> 3;            // K: key idx / V: dd idx (0..31, +32)
    const int u    = t & 7;
    const int scol = u * 8;
    const int kdstA = srow * 72 + scol;
    const int kdstB = kdstA + 32 * 72;
    // V slot base for the 8 keys u*8..u*8+7: 32*u2 + 16*u0 + 4*u1
    const int vposb = ((u >> 2) & 1) * 32 + (u & 1) * 16 + ((u >> 1) & 1) * 4;
    const int vdstA = srow * 72 + vposb;
    const int vdstB = vdstA + 32 * 72;

    f32x4 o0[4] = {}, o1[4] = {};
    f32x4 la0 = {}, la1 = {};           // l accumulators in MFMA D-layout
    float mL0 = -INFINITY, mL1 = -INFINITY;

    const f16* kbase = Kh + hb + (size_t)(z * 2048 + srow) * 64 + scol;
    const f16* vbase = Vt + hb + (size_t)srow * 4096 + z * 2048 + scol;

    half8 kregA = *(const half8*)kbase;
    half8 kregB = *(const half8*)(kbase + 2048);
    half8 vregA = *(const half8*)vbase;
    half8 vregB = *(const half8*)(vbase + (size_t)32 * 4096);

    for (int kt = 0; kt < 2048; kt += 64) {
        const int bi = (kt >> 6) & 1;
        f16* ks = &Ks[bi][0];
        f16* vs = &Vs[bi][0];

        *(half8*)&ks[kdstA] = kregA;
        *(half8*)&ks[kdstB] = kregB;
        {   // permuted V slot writes: two half4 chunks per 8-key load
            HV a_; a_.h8 = vregA;
            *(half4*)&vs[vdstA]     = a_.h4[0];
            *(half4*)&vs[vdstA + 8] = a_.h4[1];
            HV b_; b_.h8 = vregB;
            *(half4*)&vs[vdstB]     = b_.h4[0];
            *(half4*)&vs[vdstB + 8] = b_.h4[1];
        }
        __syncthreads();

        // prefetch next tile into regs (hides HBM under compute)
        int koff = ((kt + 64) & 2047);
        kregA = *(const half8*)(kbase + (size_t)koff * 64);
        kregB = *(const half8*)(kbase + 2048 + (size_t)koff * 64);
        vregA = *(const half8*)(vbase + koff);
        vregB = *(const half8*)(vbase + (size_t)32 * 4096 + koff);

        // ---- S^T = K Q^T for both q-groups; kf loaded once, used twice ----
        f32x4 sf0[4], sf1[4];
        {
            half8 kf[4];
            #pragma unroll
            for (int kb = 0; kb < 4; ++kb)
                kf[kb] = *(const half8*)&ks[(kb * 16 + lr) * 72 + lg * 8];
            __builtin_amdgcn_s_setprio(1);
            #pragma unroll
            for (int kb = 0; kb < 4; ++kb)
                sf0[kb] = __builtin_amdgcn_mfma_f32_16x16x32_f16(kf[kb], aq00, zf, 0, 0, 0);
            #pragma unroll
            for (int kb = 0; kb < 4; ++kb)
                sf1[kb] = __builtin_amdgcn_mfma_f32_16x16x32_f16(kf[kb], aq10, zf, 0, 0, 0);
            __builtin_amdgcn_s_setprio(0);
            #pragma unroll
            for (int kb = 0; kb < 4; ++kb)
                kf[kb] = *(const half8*)&ks[(kb * 16 + lr) * 72 + 32 + lg * 8];
            __builtin_amdgcn_s_setprio(1);
            #pragma unroll
            for (int kb = 0; kb < 4; ++kb)
                sf0[kb] = __builtin_amdgcn_mfma_f32_16x16x32_f16(kf[kb], aq01, sf0[kb], 0, 0, 0);
            #pragma unroll
            for (int kb = 0; kb < 4; ++kb)
                sf1[kb] = __builtin_amdgcn_mfma_f32_16x16x32_f16(kf[kb], aq11, sf1[kb], 0, 0, 0);
            __builtin_amdgcn_s_setprio(0);
        }

        // ---- max-reduce + defer ----
        max_defer(sf0, mL0, o0, la0);
        max_defer(sf1, mL1, o1, la1);

        // ---- read V^T A-fragments (plain b128, conflict-free); exp/pack
        //      VALU hides the LDS latency ----
        half8 va[4], vb_[4];
        #pragma unroll
        for (int db = 0; db < 4; ++db) {
            va[db]  = *(const half8*)&vs[(db * 16 + lr) * 72 + lg * 8];
            vb_[db] = *(const half8*)&vs[(db * 16 + lr) * 72 + 32 + lg * 8];
        }

        H8 p00, p01, p10, p11;
        exp_pack(sf0, mL0, p00, p01);
        exp_pack(sf1, mL1, p10, p11);

        // ---- O^T += V^T P^T ; l += ones x P (MFMA row-sum) ----
        __builtin_amdgcn_s_setprio(1);
        o0[0] = __builtin_amdgcn_mfma_f32_16x16x32_f16(va[0], p00.h8, o0[0], 0, 0, 0);
        o0[1] = __builtin_amdgcn_mfma_f32_16x16x32_f16(va[1], p00.h8, o0[1], 0, 0, 0);
        o0[2] = __builtin_amdgcn_mfma_f32_16x16x32_f16(va[2], p00.h8, o0[2], 0, 0, 0);
        o0[3] = __builtin_amdgcn_mfma_f32_16x16x32_f16(va[3], p00.h8, o0[3], 0, 0, 0);
        o1[0] = __builtin_amdgcn_mfma_f32_16x16x32_f16(va[0], p10.h8, o1[0], 0, 0, 0);
        o1[1] = __builtin_amdgcn_mfma_f32_16x16x32_f16(va[1], p10.h8, o1[1], 0, 0, 0);
        o1[2] = __builtin_amdgcn_mfma_f32_16x16x32_f16(va[2], p10.h8, o1[2], 0, 0, 0);
        o1[3] = __builtin_amdgcn_mfma_f32_16x16x32_f16(va[3], p10.h8, o1[3], 0, 0, 0);
        la0 = __builtin_amdgcn_mfma_f32_16x16x32_f16(ones, p00.h8, la0, 0, 0, 0);
        la1 = __builtin_amdgcn_mfma_f32_16x16x32_f16(ones, p10.h8, la1, 0, 0, 0);
        o0[0] = __builtin_amdgcn_mfma_f32_16x16x32_f16(vb_[0], p01.h8, o0[0], 0, 0, 0);
        o0[1] = __builtin_amdgcn_mfma_f32_16x16x32_f16(vb_[1], p01.h8, o0[1], 0, 0, 0);
        o0[2] = __builtin_amdgcn_mfma_f32_16x16x32_f16(vb_[2], p01.h8, o0[2], 0, 0, 0);
        o0[3] = __builtin_amdgcn_mfma_f32_16x16x32_f16(vb_[3], p01.h8, o0[3], 0, 0, 0);
        o1[0] = __builtin_amdgcn_mfma_f32_16x16x32_f16(vb_[0], p11.h8, o1[0], 0, 0, 0);
        o1[1] = __builtin_amdgcn_mfma_f32_16x16x32_f16(vb_[1], p11.h8, o1[1], 0, 0, 0);
        o1[2] = __builtin_amdgcn_mfma_f32_16x16x32_f16(vb_[2], p11.h8, o1[2], 0, 0, 0);
        o1[3] = __builtin_amdgcn_mfma_f32_16x16x32_f16(vb_[3], p11.h8, o1[3], 0, 0, 0);
        la0 = __builtin_amdgcn_mfma_f32_16x16x32_f16(ones, p01.h8, la0, 0, 0, 0);
        la1 = __builtin_amdgcn_mfma_f32_16x16x32_f16(ones, p11.h8, la1, 0, 0, 0);
        __builtin_amdgcn_s_setprio(0);
    }

    // ---- epilogue: partial X_z = O/l (no /8 here), write (b, s, h, dd) ----
    const int b = bh >> 3, h = bh & 7;
    f16* X = Xp + (size_t)z * (8192 * 512);
    const float inv0 = 1.0f / la0[0];
    const float inv1 = 1.0f / la1[0];
    const int q0_ = q0 + lr, q1_ = q0 + 16 + lr;
    #pragma unroll
    for (int db = 0; db < 4; ++db) {
        half4 hv0, hv1;
        hv0[0] = (f16)(o0[db][0] * inv0);
        hv0[1] = (f16)(o0[db][1] * inv0);
        hv0[2] = (f16)(o0[db][2] * inv0);
        hv0[3] = (f16)(o0[db][3] * inv0);
        *(half4*)&X[((size_t)(b * 4096 + q0_)) * 512 + h * 64 + db * 16 + lg * 4] = hv0;
        hv1[0] = (f16)(o1[db][0] * inv1);
        hv1[1] = (f16)(o1[db][1] * inv1);
        hv1[2] = (f16)(o1[db][2] * inv1);
        hv1[3] = (f16)(o1[db][3] * inv1);
        *(half4*)&X[((size_t)(b * 4096 + q1_)) * 512 + h * 64 + db * 16 + lg * 4] = hv1;
    }

    // (m, l) per q-row: lanes 0..15 hold la[0] = l(q0+lr); mL wave-uniform.
    if (lane < 16) {
        float2v m0v; m0v[0] = mL0; m0v[1] = la0[0];
        float2v m1v; m1v[0] = mL1; m1v[1] = la1[0];
        mlp[(size_t)z * 65536 + bh * 4096 + q0_] = m0v;
        mlp[(size_t)z * 65536 + bh * 4096 + q1_] = m1v;
    }
}

// ---------------------------------------------------------------------------
// Combine (separate kernel — measured faster than fusing into out_proj):
// X = (a1*X1 + a2*X2) / (8*(a1+a2)), a_z = exp2(m_z - mm) * l_z.
// ---------------------------------------------------------------------------
__global__ __launch_bounds__(256) void combine_halves(
    const f16* __restrict__ Xp, const float2v* __restrict__ mlp,
    f16* __restrict__ Xh)
{
    const size_t idx  = (size_t)blockIdx.x * 256 + threadIdx.x;
    const size_t flat = idx * 8;                 // (b,s,h,dd) flat offset
    const int h = (int)((flat >> 6) & 7);
    const int s = (int)((flat >> 9) & 4095);
    const int b = (int)(flat >> 21);
    const int bhq = (b * 8 + h) * 4096 + s;

    float2v ml1 = mlp[bhq];
    float2v ml2 = mlp[65536 + bhq];
    float mm = fmaxf(ml1[0], ml2[0]);
    float a1 = __builtin_amdgcn_exp2f(ml1[0] - mm) * ml1[1];
    float a2 = __builtin_amdgcn_exp2f(ml2[0] - mm) * ml2[1];
    float inv = 1.0f / (8.0f * (a1 + a2));
    float w1 = a1 * inv, w2 = a2 * inv;

    half8 x1 = *(const half8*)&Xp[flat];
    half8 x2 = *(const half8*)&Xp[(size_t)8192 * 512 + flat];
    half8 r;
    #pragma unroll
    for (int j = 0; j < 8; ++j)
        r[j] = (f16)(w1 * (float)x1[j] + w2 * (float)x2[j]);
    *(half8*)&Xh[flat] = r;
}

// ---------------------------------------------------------------------------
// Output projection: X f16 (8192x512) @ Wo^T + bo. W staged from f16.
// ---------------------------------------------------------------------------
__global__ __launch_bounds__(256) void out_proj(
    const f16* __restrict__ Xh, const f16* __restrict__ Woh,
    const float* __restrict__ bo, float* __restrict__ out)
{
    __shared__ __align__(16) f16 As[128 * 40];
    __shared__ __align__(16) f16 Ws[128 * 40];

    const int t  = threadIdx.x;
    const int m0 = blockIdx.y * 128;
    const int n0 = blockIdx.x * 128;
    const int w = t >> 6, lane = t & 63, lr = lane & 15, lg = lane >> 4;
    const int wr = w >> 1, wc = w & 1;

    f32x4 acc[4][4] = {};

    for (int k0 = 0; k0 < 512; k0 += 32) {
        #pragma unroll
        for (int it = 0; it < 2; ++it) {
            int c = t + it * 256;
            int row  = c >> 2;
            int col8 = (c & 3) * 8;

            *(half8*)&As[row * 40 + col8] =
                *(const half8*)&Xh[(size_t)(m0 + row) * 512 + k0 + col8];
            *(half8*)&Ws[row * 40 + col8] =
                *(const half8*)&Woh[(size_t)(n0 + row) * 512 + k0 + col8];
        }
        __syncthreads();

        half8 af[4], bf[4];
        #pragma unroll
        for (int i = 0; i < 4; ++i) {
            af[i] = *(const half8*)&As[(wr * 64 + i * 16 + lr) * 40 + lg * 8];
            bf[i] = *(const half8*)&Ws[(wc * 64 + i * 16 + lr) * 40 + lg * 8];
        }
        #pragma unroll
        for (int mi = 0; mi < 4; ++mi)
            #pragma unroll
            for (int ni = 0; ni < 4; ++ni)
                acc[mi][ni] = __builtin_amdgcn_mfma_f32_16x16x32_f16(af[mi], bf[ni], acc[mi][ni], 0, 0, 0);
        __syncthreads();
    }

    #pragma unroll
    for (int mi = 0; mi < 4; ++mi) {
        #pragma unroll
        for (int ni = 0; ni < 4; ++ni) {
            int col = n0 + wc * 64 + ni * 16 + lr;
            float bb = bo[col];
            #pragma unroll
            for (int r = 0; r < 4; ++r) {
                int row = m0 + wr * 64 + mi * 16 + lg * 4 + r;
                out[(size_t)row * 512 + col] = acc[mi][ni][r] + bb;
            }
        }
    }
}

// ---------------------------------------------------------------------------
extern "C" void kernel_launch(void* const* d_in, const int* in_sizes, int n_in,
                              void* d_out, int out_size, void* d_ws, size_t ws_size,
                              hipStream_t stream) {
    const float* query = (const float*)d_in[0];
    const float* key   = (const float*)d_in[1];
    const float* value = (const float*)d_in[2];
    const float* Wq    = (const float*)d_in[3];
    const float* bq    = (const float*)d_in[4];
    const float* Wk    = (const float*)d_in[5];
    const float* bk    = (const float*)d_in[6];
    const float* Wv    = (const float*)d_in[7];
    const float* bv    = (const float*)d_in[8];
    const float* Wo    = (const float*)d_in[9];
    const float* bo    = (const float*)d_in[10];
    float* out = (float*)d_out;

    char* ws = (char*)d_ws;
    f16*     Qh  = (f16*)(ws);                      //  0 MB, 8 MB (Xh overlays after flash)
    f16*     Kh  = (f16*)(ws + 8388608);            //  8 MB, 8 MB
    f16*     Vt  = (f16*)(ws + 16777216);           // 16 MB, 8 MB (transposed)
    f16*     Xp  = (f16*)(ws + 25165824);           // 24 MB, 16 MB (2 halves)
    float2v* mlp = (float2v*)(ws + 41943040);       // 40 MB, 1 MB
    f16*     Wh  = (f16*)(ws + 43008000);           // ~41 MB, 2 MB (4 matrices)
    f16*     Xh  = Qh;                              // reuse Qh (dead after flash)

    wcvt<<<dim3(128, 4), 256, 0, stream>>>(Wq, Wk, Wv, Wo, Wh);
    qkv_proj<<<dim3(4, 64, 3), 256, 0, stream>>>(query, key, value, Wh,
                                                 bq, bk, bv, Qh, Kh, Vt);
    flash_attn<<<dim3(32, 16, 2), 256, 0, stream>>>(Qh, Kh, Vt, Xp, mlp);
    combine_halves<<<2048, 256, 0, stream>>>(Xp, mlp, Xh);
    out_proj<<<dim3(4, 64), 256, 0, stream>>>(Xh, Wh + 3 * 262144, bo, out);
}

// Round 16
// 165.663 us; speedup vs baseline: 1.0285x; 1.0095x over previous
//
#include <hip/hip_runtime.h>

typedef _Float16 f16;
typedef __fp16 fp16x2 __attribute__((ext_vector_type(2)));
typedef _Float16 half4 __attribute__((ext_vector_type(4)));
typedef _Float16 half8 __attribute__((ext_vector_type(8)));
typedef float f32x4 __attribute__((ext_vector_type(4)));
typedef float float4v __attribute__((ext_vector_type(4)));
typedef float float2v __attribute__((ext_vector_type(2)));

#define LOG2E 1.44269504088896340736f

union H8 { fp16x2 h2[4]; half8 h8; };
union HV { half8 h8; half4 h4[2]; };

__device__ __forceinline__ float rowmax16(const f32x4 sf[4]) {
    float a = fmaxf(fmaxf(sf[0][0], sf[0][1]), fmaxf(sf[0][2], sf[0][3]));
    float b = fmaxf(fmaxf(sf[1][0], sf[1][1]), fmaxf(sf[1][2], sf[1][3]));
    float c = fmaxf(fmaxf(sf[2][0], sf[2][1]), fmaxf(sf[2][2], sf[2][3]));
    float d = fmaxf(fmaxf(sf[3][0], sf[3][1]), fmaxf(sf[3][2], sf[3][3]));
    return fmaxf(fmaxf(a, b), fmaxf(c, d));
}

// running-max update with defer threshold; rescales o and the MFMA-held l.
__device__ __forceinline__ void max_defer(
    const f32x4 sf[4], float& mL, f32x4 o[4], f32x4& la)
{
    float vm = rowmax16(sf);
    vm = fmaxf(vm, __shfl_xor(vm, 16, 64));
    vm = fmaxf(vm, __shfl_xor(vm, 32, 64));
    float vmL = vm * LOG2E;
    if (__any(vmL > mL + 8.0f)) {
        float mn = fmaxf(mL, vmL);
        float al = __builtin_amdgcn_exp2f(mL - mn);
        la *= al;
        #pragma unroll
        for (int db = 0; db < 4; ++db) o[db] *= al;
        mL = mn;
    }
}

// P = exp2(S*log2e - mL), packed to fp16 B-fragments (pure VALU, no lgkm).
__device__ __forceinline__ void exp_pack(
    const f32x4 sf[4], float mL, H8& pb0, H8& pb1)
{
    float pe[16];
    #pragma unroll
    for (int kb = 0; kb < 4; ++kb)
        #pragma unroll
        for (int ro = 0; ro < 4; ++ro)
            pe[kb * 4 + ro] = __builtin_amdgcn_exp2f(fmaf(sf[kb][ro], LOG2E, -mL));
    pb0.h2[0] = __builtin_amdgcn_cvt_pkrtz(pe[0],  pe[1]);
    pb0.h2[1] = __builtin_amdgcn_cvt_pkrtz(pe[2],  pe[3]);
    pb0.h2[2] = __builtin_amdgcn_cvt_pkrtz(pe[4],  pe[5]);
    pb0.h2[3] = __builtin_amdgcn_cvt_pkrtz(pe[6],  pe[7]);
    pb1.h2[0] = __builtin_amdgcn_cvt_pkrtz(pe[8],  pe[9]);
    pb1.h2[1] = __builtin_amdgcn_cvt_pkrtz(pe[10], pe[11]);
    pb1.h2[2] = __builtin_amdgcn_cvt_pkrtz(pe[12], pe[13]);
    pb1.h2[3] = __builtin_amdgcn_cvt_pkrtz(pe[14], pe[15]);
}

// ---------------------------------------------------------------------------
// QKV projection (fp32 W with cvt staging — r9-proven; no wcvt dispatch).
// Q,K written (b,h,s,dd); V written TRANSPOSED (b,h,dd,s).
// ---------------------------------------------------------------------------
__global__ __launch_bounds__(256) void qkv_proj(
    const float* __restrict__ Aq, const float* __restrict__ Ak, const float* __restrict__ Av,
    const float* __restrict__ Wq, const float* __restrict__ Wk, const float* __restrict__ Wv,
    const float* __restrict__ bq, const float* __restrict__ bk, const float* __restrict__ bv,
    f16* __restrict__ Qh, f16* __restrict__ Kh, f16* __restrict__ Vt)
{
    const int z = blockIdx.z;
    const float* __restrict__ A    = (z == 0) ? Aq : (z == 1) ? Ak : Av;
    const float* __restrict__ W    = (z == 0) ? Wq : (z == 1) ? Wk : Wv;
    const float* __restrict__ bias = (z == 0) ? bq : (z == 1) ? bk : bv;
    f16* __restrict__ dst          = (z == 0) ? Qh : (z == 1) ? Kh : Vt;

    __shared__ __align__(16) f16 As[128 * 40];
    __shared__ __align__(16) f16 Ws[128 * 40];

    const int t  = threadIdx.x;
    const int m0 = blockIdx.y * 128;
    const int n0 = blockIdx.x * 128;
    const int w = t >> 6, lane = t & 63, lr = lane & 15, lg = lane >> 4;
    const int wr = w >> 1, wc = w & 1;

    f32x4 acc[4][4] = {};

    for (int k0 = 0; k0 < 512; k0 += 32) {
        #pragma unroll
        for (int it = 0; it < 2; ++it) {
            int c = t + it * 256;
            int row  = c >> 2;
            int col8 = (c & 3) * 8;

            const float* ga = A + (size_t)(m0 + row) * 512 + k0 + col8;
            float4v a0 = *(const float4v*)ga;
            float4v a1 = *(const float4v*)(ga + 4);
            half8 ha;
            ha[0] = (f16)a0[0]; ha[1] = (f16)a0[1]; ha[2] = (f16)a0[2]; ha[3] = (f16)a0[3];
            ha[4] = (f16)a1[0]; ha[5] = (f16)a1[1]; ha[6] = (f16)a1[2]; ha[7] = (f16)a1[3];
            *(half8*)&As[row * 40 + col8] = ha;

            const float* gw = W + (size_t)(n0 + row) * 512 + k0 + col8;
            float4v w0 = *(const float4v*)gw;
            float4v w1 = *(const float4v*)(gw + 4);
            half8 hw;
            hw[0] = (f16)w0[0]; hw[1] = (f16)w0[1]; hw[2] = (f16)w0[2]; hw[3] = (f16)w0[3];
            hw[4] = (f16)w1[0]; hw[5] = (f16)w1[1]; hw[6] = (f16)w1[2]; hw[7] = (f16)w1[3];
            *(half8*)&Ws[row * 40 + col8] = hw;
        }
        __syncthreads();

        half8 af[4], bf[4];
        #pragma unroll
        for (int i = 0; i < 4; ++i) {
            af[i] = *(const half8*)&As[(wr * 64 + i * 16 + lr) * 40 + lg * 8];
            bf[i] = *(const half8*)&Ws[(wc * 64 + i * 16 + lr) * 40 + lg * 8];
        }
        #pragma unroll
        for (int mi = 0; mi < 4; ++mi)
            #pragma unroll
            for (int ni = 0; ni < 4; ++ni)
                acc[mi][ni] = __builtin_amdgcn_mfma_f32_16x16x32_f16(af[mi], bf[ni], acc[mi][ni], 0, 0, 0);
        __syncthreads();
    }

    if (z == 2) {
        // V: transposed store Vt[((b*8+h)*64 + dd)*4096 + s], half4 over r
        #pragma unroll
        for (int mi = 0; mi < 4; ++mi) {
            #pragma unroll
            for (int ni = 0; ni < 4; ++ni) {
                int col = n0 + wc * 64 + ni * 16 + lr;
                float bv_ = bias[col];
                int h  = col >> 6;
                int dd = col & 63;
                int row0 = m0 + wr * 64 + mi * 16 + lg * 4;   // 4-aligned
                int b  = row0 >> 12;
                int s0 = row0 & 4095;
                half4 hv;
                hv[0] = (f16)(acc[mi][ni][0] + bv_);
                hv[1] = (f16)(acc[mi][ni][1] + bv_);
                hv[2] = (f16)(acc[mi][ni][2] + bv_);
                hv[3] = (f16)(acc[mi][ni][3] + bv_);
                *(half4*)&dst[(((size_t)(b * 8 + h)) * 64 + dd) * 4096 + s0] = hv;
            }
        }
    } else {
        #pragma unroll
        for (int mi = 0; mi < 4; ++mi) {
            #pragma unroll
            for (int ni = 0; ni < 4; ++ni) {
                int col = n0 + wc * 64 + ni * 16 + lr;
                float bv_ = bias[col];
                int h  = col >> 6;
                int dd = col & 63;
                #pragma unroll
                for (int r = 0; r < 4; ++r) {
                    int row = m0 + wr * 64 + mi * 16 + lg * 4 + r;
                    int b = row >> 12;
                    int s = row & 4095;
                    dst[(((size_t)(b * 8 + h)) * 4096 + s) * 64 + dd] = (f16)(acc[mi][ni][r] + bv_);
                }
            }
        }
    }
}

// ---------------------------------------------------------------------------
// Flash attention v13: round-15 compute body, SINGLE-buffered LDS (18.4 KB)
// + KV-split x3 (22/21/21 key-tiles) -> grid 1536 blocks = 6 blocks/CU
// = 24 waves/CU (was 16). 2 barriers/tile; stalls filled by the 5 other
// resident blocks.
// ---------------------------------------------------------------------------
__global__ __launch_bounds__(256, 2) void flash_attn(
    const f16* __restrict__ Qh, const f16* __restrict__ Kh, const f16* __restrict__ Vt,
    f16* __restrict__ Xp, float2v* __restrict__ mlp)
{
    const int bh  = blockIdx.y;           // 0..15  (b*8 + h)
    const int z   = blockIdx.z;           // KV third
    const int t = threadIdx.x, w = t >> 6, lane = t & 63, lr = lane & 15, lg = lane >> 4;
    const int q0 = blockIdx.x * 128 + w * 32;

    const int nt  = (z == 0) ? 22 : 21;             // key-tiles in this slice
    const int kb0 = (z == 0) ? 0 : (22 + (z - 1) * 21) * 64;   // key base

    __shared__ __align__(16) f16 Ks[64 * 72];   // [key][d], stride 72
    __shared__ __align__(16) f16 Vs[64 * 72];   // [dd][slot], stride 72

    const size_t hb = (size_t)bh * (4096 * 64);

    // Q fragments (B-operand of swapped QK^T) for both 16-row groups
    half8 aq00 = *(const half8*)&Qh[hb + (size_t)(q0 + lr) * 64 + lg * 8];
    half8 aq01 = *(const half8*)&Qh[hb + (size_t)(q0 + lr) * 64 + 32 + lg * 8];
    half8 aq10 = *(const half8*)&Qh[hb + (size_t)(q0 + 16 + lr) * 64 + lg * 8];
    half8 aq11 = *(const half8*)&Qh[hb + (size_t)(q0 + 16 + lr) * 64 + 32 + lg * 8];

    // loop-invariant MFMA constants
    half8 ones;
    #pragma unroll
    for (int j = 0; j < 8; ++j) ones[j] = (f16)1.0f;
    const f32x4 zf = {0.0f, 0.0f, 0.0f, 0.0f};

    // staging: 256 threads x 2 rows x 8 f16
    const int srow = t >> 3;            // K: key idx / V: dd idx (0..31, +32)
    const int u    = t & 7;
    const int scol = u * 8;
    const int kdstA = srow * 72 + scol;
    const int kdstB = kdstA + 32 * 72;
    // V slot base for the 8 keys u*8..u*8+7: 32*u2 + 16*u0 + 4*u1
    const int vposb = ((u >> 2) & 1) * 32 + (u & 1) * 16 + ((u >> 1) & 1) * 4;
    const int vdstA = srow * 72 + vposb;
    const int vdstB = vdstA + 32 * 72;

    f32x4 o0[4] = {}, o1[4] = {};
    f32x4 la0 = {}, la1 = {};           // l accumulators in MFMA D-layout
    float mL0 = -INFINITY, mL1 = -INFINITY;

    const f16* kbase = Kh + hb + (size_t)(kb0 + srow) * 64 + scol;
    const f16* vbase = Vt + hb + (size_t)srow * 4096 + kb0 + scol;

    half8 kregA = *(const half8*)kbase;
    half8 kregB = *(const half8*)(kbase + 2048);
    half8 vregA = *(const half8*)vbase;
    half8 vregB = *(const half8*)(vbase + (size_t)32 * 4096);

    for (int it = 0; it < nt; ++it) {
        __syncthreads();                 // all waves done READING previous tile
        *(half8*)&Ks[kdstA] = kregA;
        *(half8*)&Ks[kdstB] = kregB;
        {   // permuted V slot writes: two half4 chunks per 8-key load
            HV a_; a_.h8 = vregA;
            *(half4*)&Vs[vdstA]     = a_.h4[0];
            *(half4*)&Vs[vdstA + 8] = a_.h4[1];
            HV b_; b_.h8 = vregB;
            *(half4*)&Vs[vdstB]     = b_.h4[0];
            *(half4*)&Vs[vdstB + 8] = b_.h4[1];
        }
        __syncthreads();                 // tile visible to all waves

        // prefetch next tile into regs (latency hidden under compute)
        int koff = ((it + 1 < nt) ? (it + 1) : 0) * 64;
        kregA = *(const half8*)(kbase + (size_t)koff * 64);
        kregB = *(const half8*)(kbase + 2048 + (size_t)koff * 64);
        vregA = *(const half8*)(vbase + koff);
        vregB = *(const half8*)(vbase + (size_t)32 * 4096 + koff);

        // ---- S^T = K Q^T for both q-groups; kf loaded once, used twice ----
        f32x4 sf0[4], sf1[4];
        {
            half8 kf[4];
            #pragma unroll
            for (int kb = 0; kb < 4; ++kb)
                kf[kb] = *(const half8*)&Ks[(kb * 16 + lr) * 72 + lg * 8];
            __builtin_amdgcn_s_setprio(1);
            #pragma unroll
            for (int kb = 0; kb < 4; ++kb)
                sf0[kb] = __builtin_amdgcn_mfma_f32_16x16x32_f16(kf[kb], aq00, zf, 0, 0, 0);
            #pragma unroll
            for (int kb = 0; kb < 4; ++kb)
                sf1[kb] = __builtin_amdgcn_mfma_f32_16x16x32_f16(kf[kb], aq10, zf, 0, 0, 0);
            __builtin_amdgcn_s_setprio(0);
            #pragma unroll
            for (int kb = 0; kb < 4; ++kb)
                kf[kb] = *(const half8*)&Ks[(kb * 16 + lr) * 72 + 32 + lg * 8];
            __builtin_amdgcn_s_setprio(1);
            #pragma unroll
            for (int kb = 0; kb < 4; ++kb)
                sf0[kb] = __builtin_amdgcn_mfma_f32_16x16x32_f16(kf[kb], aq01, sf0[kb], 0, 0, 0);
            #pragma unroll
            for (int kb = 0; kb < 4; ++kb)
                sf1[kb] = __builtin_amdgcn_mfma_f32_16x16x32_f16(kf[kb], aq11, sf1[kb], 0, 0, 0);
            __builtin_amdgcn_s_setprio(0);
        }

        // ---- max-reduce + defer ----
        max_defer(sf0, mL0, o0, la0);
        max_defer(sf1, mL1, o1, la1);

        // ---- read V^T A-fragments (plain b128, conflict-free) ----
        half8 va[4], vb_[4];
        #pragma unroll
        for (int db = 0; db < 4; ++db) {
            va[db]  = *(const half8*)&Vs[(db * 16 + lr) * 72 + lg * 8];
            vb_[db] = *(const half8*)&Vs[(db * 16 + lr) * 72 + 32 + lg * 8];
        }

        H8 p00, p01, p10, p11;
        exp_pack(sf0, mL0, p00, p01);
        exp_pack(sf1, mL1, p10, p11);

        // ---- O^T += V^T P^T ; l += ones x P (MFMA row-sum) ----
        __builtin_amdgcn_s_setprio(1);
        o0[0] = __builtin_amdgcn_mfma_f32_16x16x32_f16(va[0], p00.h8, o0[0], 0, 0, 0);
        o0[1] = __builtin_amdgcn_mfma_f32_16x16x32_f16(va[1], p00.h8, o0[1], 0, 0, 0);
        o0[2] = __builtin_amdgcn_mfma_f32_16x16x32_f16(va[2], p00.h8, o0[2], 0, 0, 0);
        o0[3] = __builtin_amdgcn_mfma_f32_16x16x32_f16(va[3], p00.h8, o0[3], 0, 0, 0);
        o1[0] = __builtin_amdgcn_mfma_f32_16x16x32_f16(va[0], p10.h8, o1[0], 0, 0, 0);
        o1[1] = __builtin_amdgcn_mfma_f32_16x16x32_f16(va[1], p10.h8, o1[1], 0, 0, 0);
        o1[2] = __builtin_amdgcn_mfma_f32_16x16x32_f16(va[2], p10.h8, o1[2], 0, 0, 0);
        o1[3] = __builtin_amdgcn_mfma_f32_16x16x32_f16(va[3], p10.h8, o1[3], 0, 0, 0);
        la0 = __builtin_amdgcn_mfma_f32_16x16x32_f16(ones, p00.h8, la0, 0, 0, 0);
        la1 = __builtin_amdgcn_mfma_f32_16x16x32_f16(ones, p10.h8, la1, 0, 0, 0);
        o0[0] = __builtin_amdgcn_mfma_f32_16x16x32_f16(vb_[0], p01.h8, o0[0], 0, 0, 0);
        o0[1] = __builtin_amdgcn_mfma_f32_16x16x32_f16(vb_[1], p01.h8, o0[1], 0, 0, 0);
        o0[2] = __builtin_amdgcn_mfma_f32_16x16x32_f16(vb_[2], p01.h8, o0[2], 0, 0, 0);
        o0[3] = __builtin_amdgcn_mfma_f32_16x16x32_f16(vb_[3], p01.h8, o0[3], 0, 0, 0);
        o1[0] = __builtin_amdgcn_mfma_f32_16x16x32_f16(vb_[0], p11.h8, o1[0], 0, 0, 0);
        o1[1] = __builtin_amdgcn_mfma_f32_16x16x32_f16(vb_[1], p11.h8, o1[1], 0, 0, 0);
        o1[2] = __builtin_amdgcn_mfma_f32_16x16x32_f16(vb_[2], p11.h8, o1[2], 0, 0, 0);
        o1[3] = __builtin_amdgcn_mfma_f32_16x16x32_f16(vb_[3], p11.h8, o1[3], 0, 0, 0);
        la0 = __builtin_amdgcn_mfma_f32_16x16x32_f16(ones, p01.h8, la0, 0, 0, 0);
        la1 = __builtin_amdgcn_mfma_f32_16x16x32_f16(ones, p11.h8, la1, 0, 0, 0);
        __builtin_amdgcn_s_setprio(0);
    }

    // ---- epilogue: partial X_z = O/l, write (b, s, h, dd); store (m,l) ----
    const int b = bh >> 3, h = bh & 7;
    f16* X = Xp + (size_t)z * (8192 * 512);
    const float inv0 = 1.0f / la0[0];
    const float inv1 = 1.0f / la1[0];
    const int q0_ = q0 + lr, q1_ = q0 + 16 + lr;
    #pragma unroll
    for (int db = 0; db < 4; ++db) {
        half4 hv0, hv1;
        hv0[0] = (f16)(o0[db][0] * inv0);
        hv0[1] = (f16)(o0[db][1] * inv0);
        hv0[2] = (f16)(o0[db][2] * inv0);
        hv0[3] = (f16)(o0[db][3] * inv0);
        *(half4*)&X[((size_t)(b * 4096 + q0_)) * 512 + h * 64 + db * 16 + lg * 4] = hv0;
        hv1[0] = (f16)(o1[db][0] * inv1);
        hv1[1] = (f16)(o1[db][1] * inv1);
        hv1[2] = (f16)(o1[db][2] * inv1);
        hv1[3] = (f16)(o1[db][3] * inv1);
        *(half4*)&X[((size_t)(b * 4096 + q1_)) * 512 + h * 64 + db * 16 + lg * 4] = hv1;
    }

    // (m, l) per q-row: lanes 0..15 hold la[0] = l(q0+lr); mL wave-uniform.
    if (lane < 16) {
        float2v m0v; m0v[0] = mL0; m0v[1] = la0[0];
        float2v m1v; m1v[0] = mL1; m1v[1] = la1[0];
        mlp[(size_t)z * 65536 + bh * 4096 + q0_] = m0v;
        mlp[(size_t)z * 65536 + bh * 4096 + q1_] = m1v;
    }
}

// ---------------------------------------------------------------------------
// Combine 3 partials: X = sum a_i*X_i / (8*sum a_i), a_i = exp2(m_i-mm)*l_i.
// ---------------------------------------------------------------------------
__global__ __launch_bounds__(256) void combine3(
    const f16* __restrict__ Xp, const float2v* __restrict__ mlp,
    f16* __restrict__ Xh)
{
    const size_t idx  = (size_t)blockIdx.x * 256 + threadIdx.x;
    const size_t flat = idx * 8;                 // (b,s,h,dd) flat offset
    const int h = (int)((flat >> 6) & 7);
    const int s = (int)((flat >> 9) & 4095);
    const int b = (int)(flat >> 21);
    const int bhq = (b * 8 + h) * 4096 + s;

    float2v ml0 = mlp[bhq];
    float2v ml1 = mlp[65536 + bhq];
    float2v ml2 = mlp[131072 + bhq];
    float mm = fmaxf(fmaxf(ml0[0], ml1[0]), ml2[0]);
    float a0 = __builtin_amdgcn_exp2f(ml0[0] - mm) * ml0[1];
    float a1 = __builtin_amdgcn_exp2f(ml1[0] - mm) * ml1[1];
    float a2 = __builtin_amdgcn_exp2f(ml2[0] - mm) * ml2[1];
    float inv = 1.0f / (8.0f * (a0 + a1 + a2));
    float w0 = a0 * inv, w1 = a1 * inv, w2 = a2 * inv;

    half8 x0 = *(const half8*)&Xp[flat];
    half8 x1 = *(const half8*)&Xp[(size_t)8192 * 512 + flat];
    half8 x2 = *(const half8*)&Xp[(size_t)2 * 8192 * 512 + flat];
    half8 r;
    #pragma unroll
    for (int j = 0; j < 8; ++j)
        r[j] = (f16)(w0 * (float)x0[j] + w1 * (float)x1[j] + w2 * (float)x2[j]);
    *(half8*)&Xh[flat] = r;
}

// ---------------------------------------------------------------------------
// Output projection: X f16 (8192x512) @ Wo^T + bo (fp32 W, cvt in staging).
// ---------------------------------------------------------------------------
__global__ __launch_bounds__(256) void out_proj(
    const f16* __restrict__ Xh, const float* __restrict__ Wo,
    const float* __restrict__ bo, float* __restrict__ out)
{
    __shared__ __align__(16) f16 As[128 * 40];
    __shared__ __align__(16) f16 Ws[128 * 40];

    const int t  = threadIdx.x;
    const int m0 = blockIdx.y * 128;
    const int n0 = blockIdx.x * 128;
    const int w = t >> 6, lane = t & 63, lr = lane & 15, lg = lane >> 4;
    const int wr = w >> 1, wc = w & 1;

    f32x4 acc[4][4] = {};

    for (int k0 = 0; k0 < 512; k0 += 32) {
        #pragma unroll
        for (int it = 0; it < 2; ++it) {
            int c = t + it * 256;
            int row  = c >> 2;
            int col8 = (c & 3) * 8;

            *(half8*)&As[row * 40 + col8] =
                *(const half8*)&Xh[(size_t)(m0 + row) * 512 + k0 + col8];

            const float* gw = Wo + (size_t)(n0 + row) * 512 + k0 + col8;
            float4v w0 = *(const float4v*)gw;
            float4v w1 = *(const float4v*)(gw + 4);
            half8 hw;
            hw[0] = (f16)w0[0]; hw[1] = (f16)w0[1]; hw[2] = (f16)w0[2]; hw[3] = (f16)w0[3];
            hw[4] = (f16)w1[0]; hw[5] = (f16)w1[1]; hw[6] = (f16)w1[2]; hw[7] = (f16)w1[3];
            *(half8*)&Ws[row * 40 + col8] = hw;
        }
        __syncthreads();

        half8 af[4], bf[4];
        #pragma unroll
        for (int i = 0; i < 4; ++i) {
            af[i] = *(const half8*)&As[(wr * 64 + i * 16 + lr) * 40 + lg * 8];
            bf[i] = *(const half8*)&Ws[(wc * 64 + i * 16 + lr) * 40 + lg * 8];
        }
        #pragma unroll
        for (int mi = 0; mi < 4; ++mi)
            #pragma unroll
            for (int ni = 0; ni < 4; ++ni)
                acc[mi][ni] = __builtin_amdgcn_mfma_f32_16x16x32_f16(af[mi], bf[ni], acc[mi][ni], 0, 0, 0);
        __syncthreads();
    }

    #pragma unroll
    for (int mi = 0; mi < 4; ++mi) {
        #pragma unroll
        for (int ni = 0; ni < 4; ++ni) {
            int col = n0 + wc * 64 + ni * 16 + lr;
            float bb = bo[col];
            #pragma unroll
            for (int r = 0; r < 4; ++r) {
                int row = m0 + wr * 64 + mi * 16 + lg * 4 + r;
                out[(size_t)row * 512 + col] = acc[mi][ni][r] + bb;
            }
        }
    }
}

// ---------------------------------------------------------------------------
extern "C" void kernel_launch(void* const* d_in, const int* in_sizes, int n_in,
                              void* d_out, int out_size, void* d_ws, size_t ws_size,
                              hipStream_t stream) {
    const float* query = (const float*)d_in[0];
    const float* key   = (const float*)d_in[1];
    const float* value = (const float*)d_in[2];
    const float* Wq    = (const float*)d_in[3];
    const float* bq    = (const float*)d_in[4];
    const float* Wk    = (const float*)d_in[5];
    const float* bk    = (const float*)d_in[6];
    const float* Wv    = (const float*)d_in[7];
    const float* bv    = (const float*)d_in[8];
    const float* Wo    = (const float*)d_in[9];
    const float* bo    = (const float*)d_in[10];
    float* out = (float*)d_out;

    char* ws = (char*)d_ws;
    f16*     Qh  = (f16*)(ws);                      //  0 MB, 8 MB (Xh overlays)
    f16*     Kh  = (f16*)(ws + 8388608);            //  8 MB, 8 MB
    f16*     Vt  = (f16*)(ws + 16777216);           // 16 MB, 8 MB (transposed)
    f16*     Xp  = (f16*)(ws + 25165824);           // 24 MB, 24 MB (3 partials)
    float2v* mlp = (float2v*)(ws + 50331648);       // 48 MB, 1.5 MB
    f16*     Xh  = Qh;                              // reuse Qh (dead after flash)

    qkv_proj<<<dim3(4, 64, 3), 256, 0, stream>>>(query, key, value,
                                                 Wq, Wk, Wv, bq, bk, bv,
                                                 Qh, Kh, Vt);
    flash_attn<<<dim3(32, 16, 3), 256, 0, stream>>>(Qh, Kh, Vt, Xp, mlp);
    combine3<<<2048, 256, 0, stream>>>(Xp, mlp, Xh);
    out_proj<<<dim3(4, 64), 256, 0, stream>>>(Xh, Wo, bo, out);
}